// Round 1
// baseline (832.164 us; speedup 1.0000x reference)
//
#include <hip/hip_runtime.h>
#include <stdint.h>

typedef unsigned short u16;
typedef unsigned int u32;
typedef unsigned long long u64;

typedef __attribute__((ext_vector_type(8))) __bf16 b8;   // MFMA A/B frag (8 bf16)
typedef __attribute__((ext_vector_type(4))) float f4;    // MFMA C/D frag
typedef __attribute__((ext_vector_type(4))) u32 u32x4;   // 16B copy unit

#define SCALE_F 0.17677669529663687f

// ---------- helpers ----------
__device__ __forceinline__ u16 f2bf(float f) {           // RNE f32->bf16
  u32 u = __float_as_uint(f);
  u += 0x7fffu + ((u >> 16) & 1u);
  return (u16)(u >> 16);
}
__device__ __forceinline__ u32 pk2(float a, float b) {
  return (u32)f2bf(a) | ((u32)f2bf(b) << 16);
}

__device__ __forceinline__ void gload16(const void* g, void* l) {
  // async global->LDS, 16B per lane; LDS dest = wave-uniform base + lane*16
  __builtin_amdgcn_global_load_lds(
      (__attribute__((address_space(1))) void*)(u64)g,
      (__attribute__((address_space(3))) void*)(u32)(u64)l, 16, 0, 0);
}

__device__ __forceinline__ f4 mfma16x32(b8 a, b8 b, f4 c) {
  return __builtin_amdgcn_mfma_f32_16x16x32_bf16(a, b, c, 0, 0, 0);
}

// ---------- K0: weight transpose fp32[K][N] -> bf16[N][K] ----------
__global__ __launch_bounds__(256) void k_transpose(const float* __restrict__ src,
                                                   u16* __restrict__ dst,
                                                   int K, int Nc) {
  __shared__ float tile[32][33];
  int n0 = blockIdx.x * 32, k0 = blockIdx.y * 32;
  int tx = threadIdx.x & 31, ty = threadIdx.x >> 5;
  for (int i = ty; i < 32; i += 8)
    tile[i][tx] = src[(u64)(k0 + i) * Nc + n0 + tx];
  __syncthreads();
  for (int i = ty; i < 32; i += 8)
    dst[(u64)(n0 + i) * K + k0 + tx] = f2bf(tile[tx][i]);
}

// ---------- K1: QKV GEMM  [61440,512]fp32 @ WT[1536,512]bf16 -> qkv buffer ----------
// out layout: [b][h][z(J/I)][sel(q,k,v)][n][d]  (2880 bf16 per (b,h))
__global__ __launch_bounds__(256) void k_qkv(const float* __restrict__ Aj,
                                             const float* __restrict__ Ai,
                                             const u16* __restrict__ Wj,
                                             const u16* __restrict__ Wi,
                                             u16* __restrict__ out) {
  __shared__ __align__(16) u16 As[128 * 32];
  __shared__ __align__(16) u16 Bs[128 * 32];
  __shared__ __align__(16) u16 Ct[128 * 128];

  const int t = threadIdx.x;
  const int lane = t & 63, w = t >> 6;
  const int wr = w >> 1, wc = w & 1;
  const int l16 = lane & 15, lg = lane >> 4;

  // XCD-aware swizzle: each XCD owns 60 row-panels; 12 col-tiles of a row-panel
  // run consecutively on the same XCD so the fp32 A-panel is read once into L2.
  int dflat = blockIdx.x + 12 * blockIdx.y + 5760 * blockIdx.z;
  int xcd = dflat & 7, seq = dflat >> 3;
  int z = (seq >= 720) ? 1 : 0;
  int r0 = seq - z * 720;
  int mt = xcd * 60 + r0 / 12;
  int nt = r0 - (r0 / 12) * 12;

  const float* A = z ? Ai : Aj;
  const u16* WT = z ? Wi : Wj;
  const int m0 = mt * 128;
  const int n0 = nt * 128;

  f4 acc[4][4] = {};

  const int ar = t >> 1, ah = t & 1;  // A staging: row, 16-float half

  for (int k0 = 0; k0 < 512; k0 += 32) {
    // --- B staging: 512 chunks of 16B via global_load_lds ---
    {
      int q = t;
      gload16(WT + ((u64)(n0 + (q >> 2)) * 512 + k0 + (q & 3) * 8),
              (char*)Bs + (q & ~63) * 16);
      q = t + 256;
      gload16(WT + ((u64)(n0 + (q >> 2)) * 512 + k0 + (q & 3) * 8),
              (char*)Bs + (q & ~63) * 16);
    }
    // --- A staging: 16 fp32 -> 16 bf16 per thread, 2x ds_write_b128 ---
    {
      const f4* ap = (const f4*)(A + (u64)(m0 + ar) * 512 + k0 + ah * 16);
      f4 a0 = ap[0], a1 = ap[1], a2 = ap[2], a3 = ap[3];
      u32x4 lo, hi;
      lo[0] = pk2(a0[0], a0[1]); lo[1] = pk2(a0[2], a0[3]);
      lo[2] = pk2(a1[0], a1[1]); lo[3] = pk2(a1[2], a1[3]);
      hi[0] = pk2(a2[0], a2[1]); hi[1] = pk2(a2[2], a2[3]);
      hi[2] = pk2(a3[0], a3[1]); hi[3] = pk2(a3[2], a3[3]);
      u16* dp = As + ar * 32 + ah * 16;
      *(u32x4*)(dp) = lo;
      *(u32x4*)(dp + 8) = hi;
    }
    __syncthreads();

    const u16* ab = As + (wr * 64 + l16) * 32 + lg * 8;
    const u16* bb = Bs + (wc * 64 + l16) * 32 + lg * 8;
    b8 af[4], bfr[4];
#pragma unroll
    for (int m = 0; m < 4; ++m) af[m] = *(const b8*)(ab + m * 512);
#pragma unroll
    for (int n = 0; n < 4; ++n) bfr[n] = *(const b8*)(bb + n * 512);
#pragma unroll
    for (int m = 0; m < 4; ++m)
#pragma unroll
      for (int n = 0; n < 4; ++n)
        acc[m][n] = mfma16x32(af[m], bfr[n], acc[m][n]);
    __syncthreads();
  }

  // --- epilogue: acc -> LDS tile (bf16) -> remapped vectorized stores ---
#pragma unroll
  for (int m = 0; m < 4; ++m)
#pragma unroll
    for (int n = 0; n < 4; ++n)
#pragma unroll
      for (int r2 = 0; r2 < 4; ++r2)
        Ct[(wr * 64 + m * 16 + lg * 4 + r2) * 128 + wc * 64 + n * 16 + l16] =
            f2bf(acc[m][n][r2]);
  __syncthreads();
#pragma unroll
  for (int i = 0; i < 8; ++i) {
    int q = t + i * 256;      // 2048 chunks of 8 bf16
    int row = q >> 4;
    int cc = (q & 15) * 8;
    int g = m0 + row;
    int b = g / 15, n = g - b * 15;
    int c = n0 + cc;
    int sel = c >> 9, h = (c >> 5) & 15, d0 = c & 31;
    u64 dst = ((((u64)(b * 16 + h) * 2 + z) * 3 + sel) * 15 + n) * 32 + d0;
    *(u32x4*)(out + dst) = *(const u32x4*)(Ct + q * 8);
  }
}

// ---------- K2: per-(b,h) attention, one wave each ----------
__global__ __launch_bounds__(256) void k_attn(const u16* __restrict__ qkv,
                                              const float* __restrict__ wcg,
                                              u16* __restrict__ X) {
  __shared__ __align__(16) u16 sq[4][2944];  // Jq,Jk,Jv,Iq,Ik,Iv (2880) + pad
  __shared__ __align__(16) u16 pl[4][512];   // P [16 n][32 m], cols>=15 zero
  __shared__ __align__(16) u16 jt[4][1024];  // Jv^T [32 d][32 m], m>=15 zero
  __shared__ __align__(16) u16 wct[512];     // Wconv^T [16 m][32 d], row15 zero

  const int t = threadIdx.x, lane = t & 63, w = t >> 6;
  const int l16 = lane & 15, lg = lane >> 4;
  const int bh = blockIdx.x * 4 + w;
  const int b = bh >> 4, h = bh & 15;

  for (int e = t; e < 512; e += 256) {
    int m = e >> 5, dd = e & 31;
    wct[e] = (m < 15) ? f2bf(wcg[dd * 15 + m]) : (u16)0;
  }

  const u16* src = qkv + (u64)bh * 2880;
#pragma unroll
  for (int i = 0; i < 6; ++i) {
    int chunk = i * 64 + lane;
    if (chunk < 360) gload16(src + chunk * 8, (char*)(&sq[w][0]) + i * 1024);
  }
  __syncthreads();

  const u16* q0 = &sq[w][0];
  const int foff = l16 * 32 + lg * 8;
  b8 aJ = *(const b8*)(q0 + foff);           // Jq[n][d]
  b8 bJ = *(const b8*)(q0 + 480 + foff);     // Jk[m][d]
  b8 aI = *(const b8*)(q0 + 1440 + foff);    // Iq
  b8 bI = *(const b8*)(q0 + 1920 + foff);    // Ik
  b8 aV = *(const b8*)(q0 + 2400 + foff);    // Iv
  b8 bW = *(const b8*)(wct + foff);          // Wconv^T

  f4 zero4 = {0.f, 0.f, 0.f, 0.f};
  f4 s = mfma16x32(aJ, bJ, zero4);
  s = mfma16x32(aI, bI, s);
  s = mfma16x32(aV, bW, s);
  // lane holds S[row=lg*4+r][col=l16]

  float pv[4];
  const bool cval = (l16 < 15);
#pragma unroll
  for (int r = 0; r < 4; ++r) {
    float sv = cval ? s[r] * SCALE_F : -1e30f;
    float mx = sv;
#pragma unroll
    for (int off = 1; off < 16; off <<= 1) mx = fmaxf(mx, __shfl_xor(mx, off));
    float e = __expf(sv - mx);
    float sm = e;
#pragma unroll
    for (int off = 1; off < 16; off <<= 1) sm += __shfl_xor(sm, off);
    pv[r] = e / sm;
  }

  // P -> LDS (zero k=15..31), Jv^T -> LDS
  *(u32x4*)(pl[w] + lane * 8) = (u32x4){0u, 0u, 0u, 0u};
#pragma unroll
  for (int r = 0; r < 4; ++r) pl[w][(lg * 4 + r) * 32 + l16] = f2bf(pv[r]);
#pragma unroll
  for (int i = 0; i < 16; ++i) {
    int e = i * 64 + lane;
    int dd = e >> 5, m = e & 31;
    jt[w][dd * 32 + m] = (m < 15) ? q0[960 + m * 32 + dd] : (u16)0;
  }

  b8 aP = *(const b8*)(pl[w] + foff);                      // P[n][m]
  b8 bV0 = *(const b8*)(jt[w] + l16 * 32 + lg * 8);        // Jv^T rows d=0..15
  b8 bV1 = *(const b8*)(jt[w] + (16 + l16) * 32 + lg * 8); // d=16..31
  f4 x0 = mfma16x32(aP, bV0, zero4);
  f4 x1 = mfma16x32(aP, bV1, zero4);

#pragma unroll
  for (int r = 0; r < 4; ++r) {
    int n = lg * 4 + r;
    if (n < 15) {
      u64 base = ((u64)(b * 15 + n)) * 512 + h * 32;
      X[base + l16] = f2bf(x0[r]);
      X[base + 16 + l16] = f2bf(x1[r]);
    }
  }
}

// ---------- K3: proj GEMM  X[61440,512]bf16 @ WTproj[512,512]bf16 + bias -> fp32 ----------
__global__ __launch_bounds__(256) void k_proj(const u16* __restrict__ X,
                                              const u16* __restrict__ WT,
                                              const float* __restrict__ bias,
                                              float* __restrict__ out) {
  __shared__ __align__(16) u16 As[128 * 32];
  __shared__ __align__(16) u16 Bs[128 * 32];

  const int t = threadIdx.x;
  const int lane = t & 63, w = t >> 6;
  const int wr = w >> 1, wc = w & 1;
  const int l16 = lane & 15, lg = lane >> 4;

  int dflat = blockIdx.x + 4 * blockIdx.y;
  int xcd = dflat & 7, seq = dflat >> 3;
  int mt = xcd * 60 + (seq >> 2);
  int nt = seq & 3;
  const int m0 = mt * 128, n0 = nt * 128;

  f4 acc[4][4] = {};

  for (int k0 = 0; k0 < 512; k0 += 32) {
    int q = t;
    gload16(X + ((u64)(m0 + (q >> 2)) * 512 + k0 + (q & 3) * 8),
            (char*)As + (q & ~63) * 16);
    gload16(WT + ((u64)(n0 + (q >> 2)) * 512 + k0 + (q & 3) * 8),
            (char*)Bs + (q & ~63) * 16);
    q = t + 256;
    gload16(X + ((u64)(m0 + (q >> 2)) * 512 + k0 + (q & 3) * 8),
            (char*)As + (q & ~63) * 16);
    gload16(WT + ((u64)(n0 + (q >> 2)) * 512 + k0 + (q & 3) * 8),
            (char*)Bs + (q & ~63) * 16);
    __syncthreads();

    const u16* ab = As + (wr * 64 + l16) * 32 + lg * 8;
    const u16* bb = Bs + (wc * 64 + l16) * 32 + lg * 8;
    b8 af[4], bfr[4];
#pragma unroll
    for (int m = 0; m < 4; ++m) af[m] = *(const b8*)(ab + m * 512);
#pragma unroll
    for (int n = 0; n < 4; ++n) bfr[n] = *(const b8*)(bb + n * 512);
#pragma unroll
    for (int m = 0; m < 4; ++m)
#pragma unroll
      for (int n = 0; n < 4; ++n)
        acc[m][n] = mfma16x32(af[m], bfr[n], acc[m][n]);
    __syncthreads();
  }

  float bv[4];
#pragma unroll
  for (int n = 0; n < 4; ++n) bv[n] = bias[n0 + wc * 64 + n * 16 + l16];
#pragma unroll
  for (int m = 0; m < 4; ++m)
#pragma unroll
    for (int n = 0; n < 4; ++n)
#pragma unroll
      for (int r2 = 0; r2 < 4; ++r2) {
        int row = m0 + wr * 64 + m * 16 + lg * 4 + r2;
        int col = n0 + wc * 64 + n * 16 + l16;
        out[(u64)row * 512 + col] = acc[m][n][r2] + bv[n];
      }
}

// ---------- launch ----------
extern "C" void kernel_launch(void* const* d_in, const int* in_sizes, int n_in,
                              void* d_out, int out_size, void* d_ws, size_t ws_size,
                              hipStream_t stream) {
  const float* joint    = (const float*)d_in[0];
  const float* interact = (const float*)d_in[1];
  const float* W_jqkv   = (const float*)d_in[2];
  const float* W_iqk    = (const float*)d_in[3];
  const float* W_iconv  = (const float*)d_in[4];
  const float* W_proj   = (const float*)d_in[5];
  const float* b_proj   = (const float*)d_in[6];
  float* out = (float*)d_out;

  char* ws = (char*)d_ws;
  u16* wt_j = (u16*)(ws + 0);          // [1536][512] bf16
  u16* wt_i = (u16*)(ws + 1572864);    // [1536][512]
  u16* wt_p = (u16*)(ws + 3145728);    // [512][512]
  u16* qkvb = (u16*)(ws + 3670016);    // [4096][16][2][3][15][32] bf16
  u16* Xb   = (u16*)(ws + 381157376);  // [61440][512] bf16
  // total ws use: 444,071,936 bytes

  k_transpose<<<dim3(48, 16), 256, 0, stream>>>(W_jqkv, wt_j, 512, 1536);
  k_transpose<<<dim3(48, 16), 256, 0, stream>>>(W_iqk, wt_i, 512, 1536);
  k_transpose<<<dim3(16, 16), 256, 0, stream>>>(W_proj, wt_p, 512, 512);
  k_qkv<<<dim3(12, 480, 2), 256, 0, stream>>>(joint, interact, wt_j, wt_i, qkvb);
  k_attn<<<16384, 256, 0, stream>>>(qkvb, W_iconv, Xb);
  k_proj<<<dim3(4, 480), 256, 0, stream>>>(Xb, wt_p, b_proj, out);
}

// Round 2
// 813.740 us; speedup vs baseline: 1.0226x; 1.0226x over previous
//
#include <hip/hip_runtime.h>
#include <stdint.h>

typedef unsigned short u16;
typedef unsigned int u32;
typedef unsigned long long u64;

typedef __attribute__((ext_vector_type(8))) __bf16 b8;   // MFMA A/B frag (8 bf16)
typedef __attribute__((ext_vector_type(4))) float f4;    // MFMA C/D frag
typedef __attribute__((ext_vector_type(4))) u32 u32x4;   // 16B copy unit

#define SCALE_F 0.17677669529663687f

// ---------- helpers ----------
__device__ __forceinline__ u16 f2bf(float f) {           // RNE f32->bf16 (cold paths)
  u32 u = __float_as_uint(f);
  u += 0x7fffu + ((u >> 16) & 1u);
  return (u16)(u >> 16);
}
// native cast pair -> compiler emits v_cvt_pk_bf16_f32 (RNE) [m240]
__device__ __forceinline__ u32 pk2n(float a, float b) {
  __bf16 lo = (__bf16)a, hi = (__bf16)b;
  return (u32)__builtin_bit_cast(u16, lo) | ((u32)__builtin_bit_cast(u16, hi) << 16);
}
__device__ __forceinline__ u16 f2bfn(float f) {
  __bf16 h = (__bf16)f;
  return __builtin_bit_cast(u16, h);
}

__device__ __forceinline__ void gload16(const void* g, void* l) {
  // async global->LDS, 16B per lane; LDS dest = wave-uniform base + lane*16
  __builtin_amdgcn_global_load_lds(
      (__attribute__((address_space(1))) void*)(u64)g,
      (__attribute__((address_space(3))) void*)(u32)(u64)l, 16, 0, 0);
}

__device__ __forceinline__ f4 mfma16x32(b8 a, b8 b, f4 c) {
  return __builtin_amdgcn_mfma_f32_16x16x32_bf16(a, b, c, 0, 0, 0);
}

// ---------- K0: weight transpose fp32[K][N] -> bf16[N][K] ----------
__global__ __launch_bounds__(256) void k_transpose(const float* __restrict__ src,
                                                   u16* __restrict__ dst,
                                                   int K, int Nc) {
  __shared__ float tile[32][33];
  int n0 = blockIdx.x * 32, k0 = blockIdx.y * 32;
  int tx = threadIdx.x & 31, ty = threadIdx.x >> 5;
  for (int i = ty; i < 32; i += 8)
    tile[i][tx] = src[(u64)(k0 + i) * Nc + n0 + tx];
  __syncthreads();
  for (int i = ty; i < 32; i += 8)
    dst[(u64)(n0 + i) * K + k0 + tx] = f2bf(tile[tx][i]);
}

// ---------- K1: QKV GEMM  [61440,512]fp32 @ WT[1536,512]bf16 -> qkv buffer ----------
// out layout: [b][h][z(J/I)][sel(q,k,v)][n][d]  (2880 bf16 per (b,h))
// As padded to 40 elems/row (80 B, 16B-aligned): 20*l16 mod 32 -> 8 distinct
// bank-groups over 16 lanes (2-way aliasing = free, m136). Ct unioned over
// As/Bs (epilogue-only) -> LDS 32 KB -> 5 blocks/CU.
#define ASTR 40
__global__ __launch_bounds__(256) void k_qkv(const float* __restrict__ Aj,
                                             const float* __restrict__ Ai,
                                             const u16* __restrict__ Wj,
                                             const u16* __restrict__ Wi,
                                             u16* __restrict__ out) {
  __shared__ __align__(16) char smem[32768];
  u16* As = (u16*)smem;               // [128][ASTR] padded, 10240 B
  u16* Bs = (u16*)(smem + 10240);     // [128][32], 8192 B (gload16, linear)
  u16* Ct = (u16*)smem;               // [128][128] epilogue alias, 32768 B

  const int t = threadIdx.x;
  const int lane = t & 63, w = t >> 6;
  const int wr = w >> 1, wc = w & 1;
  const int l16 = lane & 15, lg = lane >> 4;

  // XCD-aware swizzle: each XCD owns 60 row-panels; the 12 col-tiles of a
  // row-panel run consecutively on one XCD so the A-panel is L2-resident.
  int dflat = blockIdx.x + 12 * blockIdx.y + 5760 * blockIdx.z;
  int xcd = dflat & 7, seq = dflat >> 3;
  int z = (seq >= 720) ? 1 : 0;
  int r0 = seq - z * 720;
  int mt = xcd * 60 + r0 / 12;
  int nt = r0 - (r0 / 12) * 12;

  const float* A = z ? Ai : Aj;
  const u16* WT = z ? Wi : Wj;
  const int m0 = mt * 128, n0 = nt * 128;

  f4 acc[4][4] = {};
  const int ar = t >> 1, ah = t & 1;  // A staging: row, 16-float half

  for (int k0 = 0; k0 < 512; k0 += 32) {
    // --- B staging: 512 chunks of 16B via global_load_lds ---
    {
      int q = t;
      gload16(WT + ((u64)(n0 + (q >> 2)) * 512 + k0 + (q & 3) * 8),
              (char*)Bs + (q & ~63) * 16);
      q = t + 256;
      gload16(WT + ((u64)(n0 + (q >> 2)) * 512 + k0 + (q & 3) * 8),
              (char*)Bs + (q & ~63) * 16);
    }
    // --- A staging: 16 fp32 -> 16 bf16 per thread via v_cvt_pk, 2x ds_write_b128 ---
    {
      const f4* ap = (const f4*)(A + (u64)(m0 + ar) * 512 + k0 + ah * 16);
      f4 a0 = ap[0], a1 = ap[1], a2 = ap[2], a3 = ap[3];
      u32x4 lo, hi;
      lo[0] = pk2n(a0[0], a0[1]); lo[1] = pk2n(a0[2], a0[3]);
      lo[2] = pk2n(a1[0], a1[1]); lo[3] = pk2n(a1[2], a1[3]);
      hi[0] = pk2n(a2[0], a2[1]); hi[1] = pk2n(a2[2], a2[3]);
      hi[2] = pk2n(a3[0], a3[1]); hi[3] = pk2n(a3[2], a3[3]);
      u16* dp = As + ar * ASTR + ah * 16;
      *(u32x4*)(dp) = lo;
      *(u32x4*)(dp + 8) = hi;
    }
    __syncthreads();

    const u16* ab = As + (wr * 64 + l16) * ASTR + lg * 8;
    const u16* bb = Bs + (wc * 64 + l16) * 32 + lg * 8;
    b8 af[4], bfr[4];
#pragma unroll
    for (int m = 0; m < 4; ++m) af[m] = *(const b8*)(ab + m * 16 * ASTR);
#pragma unroll
    for (int n = 0; n < 4; ++n) bfr[n] = *(const b8*)(bb + n * 512);
#pragma unroll
    for (int m = 0; m < 4; ++m)
#pragma unroll
      for (int n = 0; n < 4; ++n)
        acc[m][n] = mfma16x32(af[m], bfr[n], acc[m][n]);
    __syncthreads();  // also fences the epilogue's Ct aliasing after last iter
  }

  // --- epilogue: acc -> LDS tile (bf16) -> remapped vectorized stores ---
#pragma unroll
  for (int m = 0; m < 4; ++m)
#pragma unroll
    for (int n = 0; n < 4; ++n)
#pragma unroll
      for (int r2 = 0; r2 < 4; ++r2)
        Ct[(wr * 64 + m * 16 + lg * 4 + r2) * 128 + wc * 64 + n * 16 + l16] =
            f2bfn(acc[m][n][r2]);
  __syncthreads();
#pragma unroll
  for (int i = 0; i < 8; ++i) {
    int q = t + i * 256;      // 2048 chunks of 8 bf16
    int row = q >> 4;
    int cc = (q & 15) * 8;
    int g = m0 + row;
    int b = g / 15, n = g - b * 15;
    int c = n0 + cc;
    int sel = c >> 9, h = (c >> 5) & 15, d0 = c & 31;
    u64 dst = ((((u64)(b * 16 + h) * 2 + z) * 3 + sel) * 15 + n) * 32 + d0;
    *(u32x4*)(out + dst) = *(const u32x4*)(Ct + q * 8);
  }
}

// ---------- K2: per-(b,h) attention, one wave each ----------
__global__ __launch_bounds__(256) void k_attn(const u16* __restrict__ qkv,
                                              const float* __restrict__ wcg,
                                              u16* __restrict__ X) {
  __shared__ __align__(16) u16 sq[4][2944];  // Jq,Jk,Jv,Iq,Ik,Iv (2880) + pad
  __shared__ __align__(16) u16 pl[4][512];   // P [16 n][32 m], cols>=15 zero
  __shared__ __align__(16) u16 jt[4][1024];  // Jv^T [32 d][32 m], m>=15 zero
  __shared__ __align__(16) u16 wct[512];     // Wconv^T [16 m][32 d], row15 zero

  const int t = threadIdx.x, lane = t & 63, w = t >> 6;
  const int l16 = lane & 15, lg = lane >> 4;
  const int bh = blockIdx.x * 4 + w;
  const int b = bh >> 4, h = bh & 15;

  for (int e = t; e < 512; e += 256) {
    int m = e >> 5, dd = e & 31;
    wct[e] = (m < 15) ? f2bf(wcg[dd * 15 + m]) : (u16)0;
  }

  const u16* src = qkv + (u64)bh * 2880;
#pragma unroll
  for (int i = 0; i < 6; ++i) {
    int chunk = i * 64 + lane;
    if (chunk < 360) gload16(src + chunk * 8, (char*)(&sq[w][0]) + i * 1024);
  }
  __syncthreads();

  const u16* q0 = &sq[w][0];
  const int foff = l16 * 32 + lg * 8;
  b8 aJ = *(const b8*)(q0 + foff);           // Jq[n][d]
  b8 bJ = *(const b8*)(q0 + 480 + foff);     // Jk[m][d]
  b8 aI = *(const b8*)(q0 + 1440 + foff);    // Iq
  b8 bI = *(const b8*)(q0 + 1920 + foff);    // Ik
  b8 aV = *(const b8*)(q0 + 2400 + foff);    // Iv
  b8 bW = *(const b8*)(wct + foff);          // Wconv^T

  f4 zero4 = {0.f, 0.f, 0.f, 0.f};
  f4 s = mfma16x32(aJ, bJ, zero4);
  s = mfma16x32(aI, bI, s);
  s = mfma16x32(aV, bW, s);
  // lane holds S[row=lg*4+r][col=l16]

  float pv[4];
  const bool cval = (l16 < 15);
#pragma unroll
  for (int r = 0; r < 4; ++r) {
    float sv = cval ? s[r] * SCALE_F : -1e30f;
    float mx = sv;
#pragma unroll
    for (int off = 1; off < 16; off <<= 1) mx = fmaxf(mx, __shfl_xor(mx, off));
    float e = __expf(sv - mx);
    float sm = e;
#pragma unroll
    for (int off = 1; off < 16; off <<= 1) sm += __shfl_xor(sm, off);
    pv[r] = e / sm;
  }

  // P -> LDS (zero k=15..31), Jv^T -> LDS
  *(u32x4*)(pl[w] + lane * 8) = (u32x4){0u, 0u, 0u, 0u};
#pragma unroll
  for (int r = 0; r < 4; ++r) pl[w][(lg * 4 + r) * 32 + l16] = f2bf(pv[r]);
#pragma unroll
  for (int i = 0; i < 16; ++i) {
    int e = i * 64 + lane;
    int dd = e >> 5, m = e & 31;
    jt[w][dd * 32 + m] = (m < 15) ? q0[960 + m * 32 + dd] : (u16)0;
  }

  b8 aP = *(const b8*)(pl[w] + foff);                      // P[n][m]
  b8 bV0 = *(const b8*)(jt[w] + l16 * 32 + lg * 8);        // Jv^T rows d=0..15
  b8 bV1 = *(const b8*)(jt[w] + (16 + l16) * 32 + lg * 8); // d=16..31
  f4 x0 = mfma16x32(aP, bV0, zero4);
  f4 x1 = mfma16x32(aP, bV1, zero4);

#pragma unroll
  for (int r = 0; r < 4; ++r) {
    int n = lg * 4 + r;
    if (n < 15) {
      u64 base = ((u64)(b * 15 + n)) * 512 + h * 32;
      X[base + l16] = f2bf(x0[r]);
      X[base + 16 + l16] = f2bf(x1[r]);
    }
  }
}

// ---------- K3: proj GEMM  X[61440,512]bf16 @ WTproj[512,512]bf16 + bias -> fp32 ----------
__global__ __launch_bounds__(256) void k_proj(const u16* __restrict__ X,
                                              const u16* __restrict__ WT,
                                              const float* __restrict__ bias,
                                              float* __restrict__ out) {
  __shared__ __align__(16) u16 As[128 * 32];
  __shared__ __align__(16) u16 Bs[128 * 32];

  const int t = threadIdx.x;
  const int lane = t & 63, w = t >> 6;
  const int wr = w >> 1, wc = w & 1;
  const int l16 = lane & 15, lg = lane >> 4;

  int dflat = blockIdx.x + 4 * blockIdx.y;
  int xcd = dflat & 7, seq = dflat >> 3;
  int mt = xcd * 60 + (seq >> 2);
  int nt = seq & 3;
  const int m0 = mt * 128, n0 = nt * 128;

  f4 acc[4][4] = {};

  for (int k0 = 0; k0 < 512; k0 += 32) {
    int q = t;
    gload16(X + ((u64)(m0 + (q >> 2)) * 512 + k0 + (q & 3) * 8),
            (char*)As + (q & ~63) * 16);
    gload16(WT + ((u64)(n0 + (q >> 2)) * 512 + k0 + (q & 3) * 8),
            (char*)Bs + (q & ~63) * 16);
    q = t + 256;
    gload16(X + ((u64)(m0 + (q >> 2)) * 512 + k0 + (q & 3) * 8),
            (char*)As + (q & ~63) * 16);
    gload16(WT + ((u64)(n0 + (q >> 2)) * 512 + k0 + (q & 3) * 8),
            (char*)Bs + (q & ~63) * 16);
    __syncthreads();

    const u16* ab = As + (wr * 64 + l16) * 32 + lg * 8;
    const u16* bb = Bs + (wc * 64 + l16) * 32 + lg * 8;
    b8 af[4], bfr[4];
#pragma unroll
    for (int m = 0; m < 4; ++m) af[m] = *(const b8*)(ab + m * 512);
#pragma unroll
    for (int n = 0; n < 4; ++n) bfr[n] = *(const b8*)(bb + n * 512);
#pragma unroll
    for (int m = 0; m < 4; ++m)
#pragma unroll
      for (int n = 0; n < 4; ++n)
        acc[m][n] = mfma16x32(af[m], bfr[n], acc[m][n]);
    __syncthreads();
  }

  float bv[4];
#pragma unroll
  for (int n = 0; n < 4; ++n) bv[n] = bias[n0 + wc * 64 + n * 16 + l16];
#pragma unroll
  for (int m = 0; m < 4; ++m)
#pragma unroll
    for (int n = 0; n < 4; ++n)
#pragma unroll
      for (int r2 = 0; r2 < 4; ++r2) {
        int row = m0 + wr * 64 + m * 16 + lg * 4 + r2;
        int col = n0 + wc * 64 + n * 16 + l16;
        out[(u64)row * 512 + col] = acc[m][n][r2] + bv[n];
      }
}

// ---------- launch ----------
extern "C" void kernel_launch(void* const* d_in, const int* in_sizes, int n_in,
                              void* d_out, int out_size, void* d_ws, size_t ws_size,
                              hipStream_t stream) {
  const float* joint    = (const float*)d_in[0];
  const float* interact = (const float*)d_in[1];
  const float* W_jqkv   = (const float*)d_in[2];
  const float* W_iqk    = (const float*)d_in[3];
  const float* W_iconv  = (const float*)d_in[4];
  const float* W_proj   = (const float*)d_in[5];
  const float* b_proj   = (const float*)d_in[6];
  float* out = (float*)d_out;

  char* ws = (char*)d_ws;
  u16* wt_j = (u16*)(ws + 0);          // [1536][512] bf16
  u16* wt_i = (u16*)(ws + 1572864);    // [1536][512]
  u16* wt_p = (u16*)(ws + 3145728);    // [512][512]
  u16* qkvb = (u16*)(ws + 3670016);    // [4096][16][2][3][15][32] bf16
  u16* Xb   = (u16*)(ws + 381157376);  // [61440][512] bf16
  // total ws use: 444,071,936 bytes

  k_transpose<<<dim3(48, 16), 256, 0, stream>>>(W_jqkv, wt_j, 512, 1536);
  k_transpose<<<dim3(48, 16), 256, 0, stream>>>(W_iqk, wt_i, 512, 1536);
  k_transpose<<<dim3(16, 16), 256, 0, stream>>>(W_proj, wt_p, 512, 512);
  k_qkv<<<dim3(12, 480, 2), 256, 0, stream>>>(joint, interact, wt_j, wt_i, qkvb);
  k_attn<<<16384, 256, 0, stream>>>(qkvb, W_iconv, Xb);
  k_proj<<<dim3(4, 480), 256, 0, stream>>>(Xb, wt_p, b_proj, out);
}